// Round 7
// baseline (188.487 us; speedup 1.0000x reference)
//
#include <hip/hip_runtime.h>
#include <hip/hip_fp16.h>
#include <stdint.h>

#define LOSS_IDX 8388608
#define IDX_BASE 8388609

typedef _Float16 half8 __attribute__((ext_vector_type(8)));
typedef float f32x4 __attribute__((ext_vector_type(4)));
typedef unsigned long long u64;

// ---- workspace layout (bytes) ----
#define E2_OFF   0          // 1024 * 4  code norms
#define EIMG_OFF 4096       // 1 MiB     frag-linear fp16 hi/lo emb image
//
// frag-linear image (16x16x32 MFMA A/B layout, proven R2-R6):
//   elem (row r, c): g=r>>4, m=r&15, cc=c>>5, quad=(c>>3)&3, j=c&7
//   ushort idx = (g*8+cc)*1024 + pl*512 + (quad*16+m)*8 + j
//   each (g,cc) = contiguous 2048 B block: DMA-able; frag read = lane*16B.

static __device__ __forceinline__ unsigned fkey(float d) {
    unsigned u = __float_as_uint(d);
    return u ^ ((unsigned)(((int)u) >> 31) | 0x80000000u);
}

// ---------------------------------------------------------------------------
// k1e: emb -> e-image (frag-linear hi/lo) + e2 norms + zero loss slot.
// 128 blocks x 256 thr; thread = (code, oct o): 8 c's.
// ---------------------------------------------------------------------------
__global__ __launch_bounds__(256) void k1e(
    const float* __restrict__ emb, float* __restrict__ e2,
    ushort* __restrict__ eimg, float* __restrict__ out) {
    int tid = blockIdx.x * 256 + threadIdx.x;      // 0..32767
    if (tid == 0) out[LOSS_IDX] = 0.f;             // re-zero every call
    int code = tid >> 5, o = tid & 31;
    const float4 v0 = *(const float4*)&emb[code * 256 + o * 8];
    const float4 v1 = *(const float4*)&emb[code * 256 + o * 8 + 4];
    float v[8] = {v0.x, v0.y, v0.z, v0.w, v1.x, v1.y, v1.z, v1.w};
    float s = 0.f;
    half8 hi, lo;
    #pragma unroll
    for (int j = 0; j < 8; ++j) {
        s = fmaf(v[j], v[j], s);
        __half h = __float2half(v[j]);             // RNE
        __half l = __float2half(v[j] - __half2float(h));
        hi[j] = *(_Float16*)&h;
        lo[j] = *(_Float16*)&l;
    }
    int g = code >> 4, m = code & 15, cc = o >> 2, quad = o & 3;
    int base = (g * 8 + cc) * 1024 + (quad * 16 + m) * 8;
    *(half8*)&eimg[base] = hi;
    *(half8*)&eimg[base + 512] = lo;               // pl=1 plane
    #pragma unroll
    for (int msk = 1; msk <= 16; msk <<= 1) s += __shfl_xor(s, msk, 64);
    if (o == 0) e2[code] = s;
}

// ---------------------------------------------------------------------------
// kmega: one block = 64 queries x ALL 1024 codes. 512 blocks x 256 thr.
//  phase A: z (64q x 256c) -> LDS A-image (hi/lo fp16 frag layout) + sum z^2
//  main:    cg loop x4 { cc loop x8: B 32KB dbuf DMA + 48 MFMA/wave }
//           per-cg argmin epilogue -> LDS winb (block owns its q fully)
//  final:   indices + loss (d'win from key + z^2) + res scatter (fused k3)
// No z-image in HBM, no winner table, no cross-block dependencies.
// ---------------------------------------------------------------------------
__global__ __launch_bounds__(256) void kmega(
    const float* __restrict__ z_e, const float* __restrict__ emb,
    const ushort* __restrict__ eimg, const float* __restrict__ e2g,
    float* __restrict__ out) {
    __shared__ __attribute__((aligned(16))) ushort as_[32768];      // 64 KB A image
    __shared__ __attribute__((aligned(16))) ushort bs_[2][16384];   // 2x32 KB B dbuf
    __shared__ u64 winb[64];
    __shared__ float red[4];

    int t = threadIdx.x;
    int lane = t & 63, w = t >> 6;
    int qbase = blockIdx.x * 64;
    int b = qbase >> 10, hw0 = qbase & 1023;
    const float* zb = z_e + b * (256 * 1024) + hw0;

    if (t < 64) winb[t] = ~0ull;

    // ---- B-chunk DMA: 16 ng-blocks x 2048 B from e-image ----
    auto issueB = [&](int cg2, int cc2, int p) {
        #pragma unroll
        for (int i = 0; i < 8; ++i) {
            int u = i * 256 + t;
            int ng = u >> 7, inner = u & 127;
            const char* src = (const char*)eimg +
                (size_t)((cg2 * 16 + ng) * 8 + cc2) * 2048 + inner * 16;
            __builtin_amdgcn_global_load_lds(
                (const __attribute__((address_space(1))) unsigned int*)src,
                (__attribute__((address_space(3))) unsigned int*)((char*)bs_[p] + u * 16),
                16, 0, 0);
        }
    };

    issueB(0, 0, 0);                    // prefetch first chunk under phase A

    // ---- phase A: z -> A-image in LDS + z^2 ----
    int q = lane, og = w;               // wave w handles c in [og*64, og*64+64)
    int gl = q >> 4, m = q & 15;
    float z2acc = 0.f;
    #pragma unroll
    for (int oi = 0; oi < 8; ++oi) {
        int c0 = og * 64 + oi * 8;
        float v[8];
        #pragma unroll
        for (int j = 0; j < 8; ++j) v[j] = zb[(c0 + j) * 1024 + q];  // coalesced 256B
        half8 hi, lo;
        #pragma unroll
        for (int j = 0; j < 8; ++j) {
            z2acc = fmaf(v[j], v[j], z2acc);
            __half h = __float2half(v[j]);
            __half l = __float2half(v[j] - __half2float(h));
            hi[j] = *(_Float16*)&h;
            lo[j] = *(_Float16*)&l;
        }
        int cc = c0 >> 5, quad = (c0 >> 3) & 3;
        int base = (gl * 8 + cc) * 1024 + (quad * 16 + m) * 8;
        *(half8*)&as_[base] = hi;
        *(half8*)&as_[base + 512] = lo;
    }

    // ---- main loop: 4 cg x 8 cc; wave tile 64q x 64k (mt4 x nt4) ----
    int nh = w;                          // wave's 64-code quarter of the cg
    int lm = lane & 15, lg = lane >> 4;
    for (int cg = 0; cg < 4; ++cg) {
        f32x4 acc[4][4];
        #pragma unroll
        for (int mt = 0; mt < 4; ++mt)
            #pragma unroll
            for (int nt = 0; nt < 4; ++nt) acc[mt][nt] = (f32x4){0.f, 0.f, 0.f, 0.f};
        for (int cc = 0; cc < 8; ++cc) {
            int step = cg * 8 + cc;
            int buf = step & 1;
            __syncthreads();             // drains DMA(step) (+ phase A at step 0)
            if (step < 31) {
                int s = step + 1;
                issueB(s >> 3, s & 7, s & 1);
            }
            half8 ah[4], al[4];
            #pragma unroll
            for (int mt = 0; mt < 4; ++mt) {
                int base = (mt * 8 + cc) * 1024 + lane * 8;
                ah[mt] = *(const half8*)&as_[base];
                al[mt] = *(const half8*)&as_[base + 512];
            }
            #pragma unroll
            for (int nt = 0; nt < 4; ++nt) {
                int base = (nh * 4 + nt) * 1024 + lane * 8;
                half8 bh = *(const half8*)&bs_[buf][base];
                half8 bl = *(const half8*)&bs_[buf][base + 512];
                #pragma unroll
                for (int mt = 0; mt < 4; ++mt) {
                    acc[mt][nt] = __builtin_amdgcn_mfma_f32_16x16x32_f16(ah[mt], bh, acc[mt][nt], 0, 0, 0);
                    acc[mt][nt] = __builtin_amdgcn_mfma_f32_16x16x32_f16(ah[mt], bl, acc[mt][nt], 0, 0, 0);
                    acc[mt][nt] = __builtin_amdgcn_mfma_f32_16x16x32_f16(al[mt], bh, acc[mt][nt], 0, 0, 0);
                }
            }
        }
        // ---- per-cg argmin epilogue (C: col=lane&15 -> code, row=lg*4+r -> q)
        float e2v[4];
        #pragma unroll
        for (int nt = 0; nt < 4; ++nt)
            e2v[nt] = e2g[cg * 256 + nh * 64 + nt * 16 + lm];
        #pragma unroll
        for (int mt = 0; mt < 4; ++mt)
            #pragma unroll
            for (int r = 0; r < 4; ++r) {
                u64 best = ~0ull;
                #pragma unroll
                for (int nt = 0; nt < 4; ++nt) {
                    float d = fmaf(-2.f, acc[mt][nt][r], e2v[nt]);
                    u64 p = ((u64)fkey(d) << 32) |
                            (unsigned)(cg * 256 + nh * 64 + nt * 16 + lm);
                    if (p < best) best = p;
                }
                #pragma unroll
                for (int msk = 1; msk <= 8; msk <<= 1) {   // reduce 16 lm lanes
                    unsigned blo = __shfl_xor((unsigned)best, msk, 64);
                    unsigned bhi = __shfl_xor((unsigned)(best >> 32), msk, 64);
                    u64 p = ((u64)bhi << 32) | blo;
                    if (p < best) best = p;
                }
                if (lm == 0) atomicMin(&winb[mt * 16 + lg * 4 + r], best);
            }
    }
    __syncthreads();                     // winb final

    // ---- indices + loss ----
    float dsum = 0.f;
    if (t < 64) {                        // wave 0
        u64 p = winb[t];
        out[IDX_BASE + qbase + t] = (float)(int)(p & 0xFFFFFFFFull);
        unsigned key = (unsigned)(p >> 32);
        unsigned u = (key & 0x80000000u) ? (key ^ 0x80000000u) : ~key;
        dsum = __uint_as_float(u);       // d'win = (zq-z)^2 - z^2
    }
    float s = z2acc;
    #pragma unroll
    for (int off = 32; off > 0; off >>= 1) s += __shfl_down(s, off, 64);
    if (lane == 0) red[w] = s;
    #pragma unroll
    for (int off = 32; off > 0; off >>= 1) dsum += __shfl_down(dsum, off, 64);
    __syncthreads();
    if (t == 0)
        atomicAdd(&out[LOSS_IDX],
                  (red[0] + red[1] + red[2] + red[3] + dsum) * (1.25f / 8388608.f));

    // ---- fused res scatter: emb[k*] -> (b,c,h,w), float4 along hw ----
    float* lsc = (float*)as_;            // reuse A-image: [c][row] stride 67
    float* rb = out + b * (256 * 1024) + hw0;
    for (int ch = 0; ch < 4; ++ch) {
        int cbase = ch * 64;
        __syncthreads();
        #pragma unroll
        for (int i = 0; i < 4; ++i) {    // gather 64 rows x 64 c (float4)
            int u = i * 256 + t;
            int row = u >> 4, cq = u & 15;
            int kk = (int)(winb[row] & 0xFFFFFFFFull);
            float4 v = *(const float4*)&emb[kk * 256 + cbase + cq * 4];
            int c0 = cq * 4;
            lsc[(c0 + 0) * 67 + row] = v.x;
            lsc[(c0 + 1) * 67 + row] = v.y;
            lsc[(c0 + 2) * 67 + row] = v.z;
            lsc[(c0 + 3) * 67 + row] = v.w;
        }
        __syncthreads();
        #pragma unroll
        for (int i = 0; i < 4; ++i) {    // store: 64 c x 16 hw-float4
            int u = i * 256 + t;
            int c = u >> 4, h4 = u & 15;
            float4 o;
            o.x = lsc[c * 67 + h4 * 4 + 0];
            o.y = lsc[c * 67 + h4 * 4 + 1];
            o.z = lsc[c * 67 + h4 * 4 + 2];
            o.w = lsc[c * 67 + h4 * 4 + 3];
            *(float4*)&rb[(cbase + c) * 1024 + h4 * 4] = o;
        }
    }
}

// ---------------------------------------------------------------------------
extern "C" void kernel_launch(void* const* d_in, const int* in_sizes, int n_in,
                              void* d_out, int out_size, void* d_ws, size_t ws_size,
                              hipStream_t stream) {
    const float* z_e = (const float*)d_in[0];   // (32,256,32,32) fp32
    const float* emb = (const float*)d_in[1];   // (1024,256) fp32
    float* out = (float*)d_out;
    float*  e2   = (float*)((char*)d_ws + E2_OFF);
    ushort* eimg = (ushort*)((char*)d_ws + EIMG_OFF);

    k1e  <<<128, 256, 0, stream>>>(emb, e2, eimg, out);
    kmega<<<512, 256, 0, stream>>>(z_e, emb, eimg, e2, out);
}